// Round 1
// 902.895 us; speedup vs baseline: 1.4924x; 1.4924x over previous
//
#include <hip/hip_runtime.h>
#include <stdint.h>

#define TT 7
#define CC 256
#define NPOSC 36864   // B*H*W = 4*96*96

typedef unsigned int uint;
typedef unsigned short ushort_t;
typedef __attribute__((ext_vector_type(8))) short short8;
typedef __attribute__((ext_vector_type(4))) float f32x4;

__device__ inline float bf2f(ushort_t u) {
    union { uint i; float f; } v; v.i = ((uint)u) << 16; return v.f;
}
__device__ inline ushort_t f2bf(float f) {
    union { float f; uint i; } v; v.f = f;
    uint i = v.i;
    return (ushort_t)((i + 0x7FFFu + ((i >> 16) & 1u)) >> 16);
}
__device__ inline uint pack2(float a, float b) {
    return (uint)f2bf(a) | (((uint)f2bf(b)) << 16);
}
__device__ inline short8 as_s8(uint4 v) {
    union { uint4 u; short8 s; } x; x.u = v; return x.s;
}

// ---------------------------------------------------------------------------
// prep: blocks 0..63  -> 64x64-tile transposes (fp32 -> bf16) of Wq,Wk,Wv
//                        -> WTall[768][256]; Wo -> WoT[c][nd]
//       blocks 64..84 -> biasC[t][768] = {bq, bk, bv - emb[t]*Wv}   (fp32)
// ---------------------------------------------------------------------------
__global__ void prep_kernel(const float* __restrict__ Wq, const float* __restrict__ Wk,
                            const float* __restrict__ Wv, const float* __restrict__ Wo,
                            const float* __restrict__ bq, const float* __restrict__ bk,
                            const float* __restrict__ bv, const float* __restrict__ temb,
                            ushort_t* __restrict__ WTall, ushort_t* __restrict__ WoT,
                            float* __restrict__ biasC)
{
    int bx = blockIdx.x, tid = threadIdx.x;
    if (bx < 64) {
        __shared__ __align__(16) ushort_t tl[64][72];   // 72*2=144B row stride (16B-mult)
        int m = bx >> 4, tile = bx & 15;
        int tr = (tile >> 2) * 64, tc = (tile & 3) * 64;
        const float* src = (m == 0) ? Wq : (m == 1) ? Wk : (m == 2) ? Wv : Wo;
        ushort_t* dst = (m < 3) ? (WTall + m * 65536) : WoT;
        int lr = tid >> 2, lc = (tid & 3) * 16;
        const float* sp = src + (size_t)(tr + lr) * 256 + tc + lc;
        #pragma unroll
        for (int q = 0; q < 4; ++q) {
            float4 x = *(const float4*)(sp + q * 4);
            tl[lr][lc + q * 4 + 0] = f2bf(x.x);
            tl[lr][lc + q * 4 + 1] = f2bf(x.y);
            tl[lr][lc + q * 4 + 2] = f2bf(x.z);
            tl[lr][lc + q * 4 + 3] = f2bf(x.w);
        }
        __syncthreads();
        uint w[8];
        #pragma unroll
        for (int j = 0; j < 8; ++j) {
            ushort_t e0 = tl[lc + 2 * j][lr];
            ushort_t e1 = tl[lc + 2 * j + 1][lr];
            w[j] = (uint)e0 | ((uint)e1 << 16);
        }
        uint4 o0, o1;
        o0.x = w[0]; o0.y = w[1]; o0.z = w[2]; o0.w = w[3];
        o1.x = w[4]; o1.y = w[5]; o1.z = w[6]; o1.w = w[7];
        *(uint4*)(dst + (size_t)(tc + lr) * 256 + tr + lc) = o0;
        *(uint4*)(dst + (size_t)(tc + lr) * 256 + tr + lc + 8) = o1;
    } else {
        int gid = (bx - 64) * 256 + tid;   // 0..5375
        int t = gid / 768, j = gid % 768;
        float val;
        if (j < 256) {
            val = bq[j];
        } else if (j < 512) {
            val = bk[j - 256];
        } else {
            int nd = j - 512;
            float acc = bv[nd];
            for (int c = 0; c < 256; ++c)
                acc -= temb[t * 256 + c] * Wv[(size_t)c * 256 + nd];
            val = acc;   // bv - emb*Wv  => V = (X+emb)*Wv + biasC
        }
        biasC[t * 768 + j] = val;
    }
}

// ---------------------------------------------------------------------------
// K1: qkvT[nd=768][t][pos] = WTall[nd][c] x bf16(frames[t][pos][c] + emb[t][c])
//                            + biasC     (fp32 in, bf16 out)
// ---------------------------------------------------------------------------
__launch_bounds__(256, 2)
__global__ void qkv_kernel(const float* __restrict__ frames, const float* __restrict__ temb,
                           const ushort_t* __restrict__ WTall, const float* __restrict__ biasC,
                           ushort_t* __restrict__ qkvT, int posBase, int Ps)
{
    int t = blockIdx.y;
    int pos0l = blockIdx.x * 128;
    int tid = threadIdx.x;
    int wave = tid >> 6, lane = tid & 63;
    int mh = wave >> 1, nh = wave & 1;
    int l15 = lane & 15, lg = lane >> 4;

    __shared__ __align__(16) ushort_t Atile[2][64][40];   // 40*2=80B stride (16B-mult)

    // --- load B fragments: KQ^T = frames + emb, 64 pos x 256 c per wave ---
    uint4 Breg[4][8];
    {
        const float* fb = frames + ((size_t)t * NPOSC + posBase + pos0l + nh * 64) * 256;
        #pragma unroll
        for (int kc = 0; kc < 8; ++kc) {
            float4 e0 = *(const float4*)(temb + t * 256 + kc * 32 + lg * 8);
            float4 e1 = *(const float4*)(temb + t * 256 + kc * 32 + lg * 8 + 4);
            #pragma unroll
            for (int nt = 0; nt < 4; ++nt) {
                const float* xp = fb + (size_t)(nt * 16 + l15) * 256 + kc * 32 + lg * 8;
                float4 x0 = *(const float4*)(xp);
                float4 x1 = *(const float4*)(xp + 4);
                uint4 r;
                r.x = pack2(x0.x + e0.x, x0.y + e0.y);
                r.y = pack2(x0.z + e0.z, x0.w + e0.w);
                r.z = pack2(x1.x + e1.x, x1.y + e1.y);
                r.w = pack2(x1.z + e1.z, x1.w + e1.w);
                Breg[nt][kc] = r;
            }
        }
    }

    f32x4 acc[2][4];
    const f32x4 z4 = {0.f, 0.f, 0.f, 0.f};
    #pragma unroll
    for (int mt = 0; mt < 2; ++mt)
        #pragma unroll
        for (int nt = 0; nt < 4; ++nt) acc[mt][nt] = z4;

    int srow = tid >> 2, sq4 = tid & 3;

    // prologue: stage (ndc=0,kc=0) into buffer 0
    {
        uint4 sv = *(const uint4*)(WTall + (size_t)srow * 256 + sq4 * 8);
        *(uint4*)&Atile[0][srow][sq4 * 8] = sv;
    }

    for (int ndc = 0; ndc < 12; ++ndc) {
        #pragma unroll
        for (int kc = 0; kc < 8; ++kc) {
            int it = ndc * 8 + kc;
            int buf = kc & 1;
            uint4 nxt;
            bool have = (it + 1 < 96);
            if (have) {
                int it1 = it + 1;
                nxt = *(const uint4*)(WTall + ((size_t)((it1 >> 3) * 64 + srow)) * 256
                                      + (it1 & 7) * 32 + sq4 * 8);
            }
            __syncthreads();
            if (have) *(uint4*)&Atile[buf ^ 1][srow][sq4 * 8] = nxt;

            uint4 af[2];
            #pragma unroll
            for (int mt = 0; mt < 2; ++mt)
                af[mt] = *(const uint4*)&Atile[buf][mh * 32 + mt * 16 + l15][lg * 8];
            #pragma unroll
            for (int mt = 0; mt < 2; ++mt)
                #pragma unroll
                for (int nt = 0; nt < 4; ++nt)
                    acc[mt][nt] = __builtin_amdgcn_mfma_f32_16x16x32_bf16(
                        as_s8(af[mt]), as_s8(Breg[nt][kc]), acc[mt][nt], 0, 0, 0);
        }
        // epilogue for this nd-chunk (64 rows)
        #pragma unroll
        for (int mt = 0; mt < 2; ++mt) {
            int ndbase = ndc * 64 + mh * 32 + mt * 16 + lg * 4;
            float bi[4];
            #pragma unroll
            for (int i = 0; i < 4; ++i) bi[i] = biasC[t * 768 + ndbase + i];
            #pragma unroll
            for (int nt = 0; nt < 4; ++nt) {
                int posl = pos0l + nh * 64 + nt * 16 + l15;
                #pragma unroll
                for (int i = 0; i < 4; ++i) {
                    float v = acc[mt][nt][i] + bi[i];
                    qkvT[((size_t)(ndbase + i) * 7 + t) * Ps + posl] = f2bf(v);
                }
                acc[mt][nt] = z4;
            }
        }
    }
}

// ---------------------------------------------------------------------------
// K2: attention per (pos, head). lane = position -> fully coalesced loads.
// qkvT rows: q = nd, k = 256+nd, v = 512+nd
// NEW: ctx written TRANSPOSED as ctxT[c][a*Ps+pos]  (pos-contiguous scalar
// stores -> 128B contiguous per wave store, write traffic at the 132 MB ideal)
// ---------------------------------------------------------------------------
__global__ void attn_kernel(const ushort_t* __restrict__ qkvT, ushort_t* __restrict__ ctxT, int Ps)
{
    int n = blockIdx.y;
    int pos = blockIdx.x * 256 + threadIdx.x;
    const float scale = 0.17677669529663687f;      // 1/sqrt(32)
    float s[7][7];
    #pragma unroll
    for (int a = 0; a < 7; ++a)
        #pragma unroll
        for (int b = 0; b < 7; ++b) s[a][b] = 0.f;

    const ushort_t* qp = qkvT + ((size_t)(n * 32) * 7) * Ps + pos;
    const ushort_t* kp = qkvT + ((size_t)(256 + n * 32) * 7) * Ps + pos;

    for (int d = 0; d < 32; ++d) {
        float qv[7], kv[7];
        #pragma unroll
        for (int i = 0; i < 7; ++i) qv[i] = bf2f(qp[(size_t)(d * 7 + i) * Ps]);
        #pragma unroll
        for (int i = 0; i < 7; ++i) kv[i] = bf2f(kp[(size_t)(d * 7 + i) * Ps]);
        #pragma unroll
        for (int a = 0; a < 7; ++a)
            #pragma unroll
            for (int b = 0; b < 7; ++b) s[a][b] += qv[a] * kv[b];
    }

    #pragma unroll
    for (int a = 0; a < 7; ++a) {
        float mx = -1e30f;
        #pragma unroll
        for (int b = 0; b < 7; ++b) { s[a][b] *= scale; mx = fmaxf(mx, s[a][b]); }
        float sum = 0.f;
        #pragma unroll
        for (int b = 0; b < 7; ++b) {
            float e = exp2f((s[a][b] - mx) * 1.4426950408889634f);
            s[a][b] = e; sum += e;
        }
        float r = 1.0f / sum;
        #pragma unroll
        for (int b = 0; b < 7; ++b) s[a][b] *= r;
    }

    const ushort_t* vp = qkvT + ((size_t)(512 + n * 32) * 7) * Ps + pos;
    const size_t K7P = (size_t)7 * Ps;
    ushort_t* cb = ctxT + (size_t)(n * 32) * K7P + pos;

    #pragma unroll
    for (int dc = 0; dc < 4; ++dc) {
        float o[7][8];
        #pragma unroll
        for (int a = 0; a < 7; ++a)
            #pragma unroll
            for (int j = 0; j < 8; ++j) o[a][j] = 0.f;
        #pragma unroll
        for (int kt = 0; kt < 7; ++kt) {
            float vv[8];
            #pragma unroll
            for (int j = 0; j < 8; ++j)
                vv[j] = bf2f(vp[(size_t)((dc * 8 + j) * 7 + kt) * Ps]);
            #pragma unroll
            for (int a = 0; a < 7; ++a)
                #pragma unroll
                for (int j = 0; j < 8; ++j) o[a][j] += s[a][kt] * vv[j];
        }
        // transposed store: channel-major, pos contiguous -> coalesced
        #pragma unroll
        for (int j = 0; j < 8; ++j) {
            ushort_t* cj = cb + (size_t)(dc * 8 + j) * K7P;
            #pragma unroll
            for (int a = 0; a < 7; ++a)
                cj[(size_t)a * Ps] = f2bf(o[a][j]);
        }
    }
}

// ---------------------------------------------------------------------------
// K3: out[t*NPOS+pos][c] = ctxT[nd][tp] x Wo[nd][c] + bo[c]   (fp32 output)
// A = ctxT (pos-contig global reads, transposed into LDS with XOR col-group
// swizzle: stored group = logical group ^ ((row>>3)&3)), B = WoT (k-contig).
// ---------------------------------------------------------------------------
__launch_bounds__(256, 2)
__global__ void out_kernel(const ushort_t* __restrict__ ctxT, const ushort_t* __restrict__ WoT,
                           const float* __restrict__ bo, float* __restrict__ outp,
                           int posBase, int Ps)
{
    int rows0 = blockIdx.x * 128;
    int c0 = blockIdx.y * 128;
    int tid = threadIdx.x, wave = tid >> 6, lane = tid & 63;
    int mh = wave >> 1, nh = wave & 1;
    int l15 = lane & 15, lg = lane >> 4;
    const size_t K7P = (size_t)7 * Ps;

    __shared__ __align__(16) ushort_t At[2][128][40];
    __shared__ __align__(16) ushort_t Bt[2][128][40];

    // A staging mapping: each thread owns one nd column, 2x8 consecutive rows
    int ndl = tid >> 3;          // 0..31  (k within chunk)
    int rg  = tid & 7;           // 0..7   (row octet)
    // swizzled LDS column for this thread's nd (constant: (row>>3)&3 == rg&3
    // for both row halves rg*8+i and 64+rg*8+i)
    int csw = ((((ndl >> 3) ^ (rg & 3)) << 3) | (ndl & 7));

    f32x4 acc[4][4];
    const f32x4 z4 = {0.f, 0.f, 0.f, 0.f};
    #pragma unroll
    for (int mt = 0; mt < 4; ++mt)
        #pragma unroll
        for (int nt = 0; nt < 4; ++nt) acc[mt][nt] = z4;

    // stage kc=0
    {
        const ushort_t* ap = ctxT + (size_t)ndl * K7P + rows0 + rg * 8;
        union { uint4 u; ushort_t s[8]; } ua, ub;
        ua.u = *(const uint4*)ap;
        ub.u = *(const uint4*)(ap + 64);
        #pragma unroll
        for (int i = 0; i < 8; ++i) {
            At[0][rg * 8 + i][csw] = ua.s[i];
            At[0][64 + rg * 8 + i][csw] = ub.s[i];
        }
        #pragma unroll
        for (int p = 0; p < 2; ++p) {
            int ch = p * 256 + tid, row = ch >> 2, q4 = ch & 3;
            uint4 bv_ = *(const uint4*)(WoT + (size_t)(c0 + row) * 256 + q4 * 8);
            *(uint4*)&Bt[0][row][q4 * 8] = bv_;
        }
    }

    #pragma unroll
    for (int kc = 0; kc < 8; ++kc) {
        int buf = kc & 1;
        uint4 na0, na1, nb[2];
        if (kc < 7) {
            const ushort_t* ap = ctxT + (size_t)((kc + 1) * 32 + ndl) * K7P + rows0 + rg * 8;
            na0 = *(const uint4*)ap;
            na1 = *(const uint4*)(ap + 64);
            #pragma unroll
            for (int p = 0; p < 2; ++p) {
                int ch = p * 256 + tid, row = ch >> 2, q4 = ch & 3;
                nb[p] = *(const uint4*)(WoT + (size_t)(c0 + row) * 256 + (kc + 1) * 32 + q4 * 8);
            }
        }
        __syncthreads();
        if (kc < 7) {
            union { uint4 u; ushort_t s[8]; } ua, ub;
            ua.u = na0; ub.u = na1;
            #pragma unroll
            for (int i = 0; i < 8; ++i) {
                At[buf ^ 1][rg * 8 + i][csw] = ua.s[i];
                At[buf ^ 1][64 + rg * 8 + i][csw] = ub.s[i];
            }
            #pragma unroll
            for (int p = 0; p < 2; ++p) {
                int ch = p * 256 + tid, row = ch >> 2, q4 = ch & 3;
                *(uint4*)&Bt[buf ^ 1][row][q4 * 8] = nb[p];
            }
        }
        uint4 af[4], bfr[4];
        #pragma unroll
        for (int mt = 0; mt < 4; ++mt) {
            int r = mh * 64 + mt * 16 + l15;
            af[mt] = *(const uint4*)&At[buf][r][(lg ^ ((r >> 3) & 3)) << 3];
        }
        #pragma unroll
        for (int nt = 0; nt < 4; ++nt)
            bfr[nt] = *(const uint4*)&Bt[buf][nh * 64 + nt * 16 + l15][lg * 8];
        #pragma unroll
        for (int mt = 0; mt < 4; ++mt)
            #pragma unroll
            for (int nt = 0; nt < 4; ++nt)
                acc[mt][nt] = __builtin_amdgcn_mfma_f32_16x16x32_bf16(
                    as_s8(af[mt]), as_s8(bfr[nt]), acc[mt][nt], 0, 0, 0);
    }

    int t = rows0 / Ps;            // block entirely inside one t (Ps % 128 == 0)
    int prow = rows0 - t * Ps;
    size_t obase = (size_t)t * NPOSC + posBase + prow;
    #pragma unroll
    for (int nt = 0; nt < 4; ++nt) {
        int col = c0 + nh * 64 + nt * 16 + l15;
        float bov = bo[col];
        #pragma unroll
        for (int mt = 0; mt < 4; ++mt) {
            #pragma unroll
            for (int i = 0; i < 4; ++i) {
                int r = mh * 64 + mt * 16 + lg * 4 + i;
                outp[(obase + r) * 256 + col] = acc[mt][nt][i] + bov;
            }
        }
    }
}

// ---------------------------------------------------------------------------
extern "C" void kernel_launch(void* const* d_in, const int* in_sizes, int n_in,
                              void* d_out, int out_size, void* d_ws, size_t ws_size,
                              hipStream_t stream)
{
    const float* frames = (const float*)d_in[0];
    const float* temb   = (const float*)d_in[1];
    const float* Wq = (const float*)d_in[2];
    const float* bq = (const float*)d_in[3];
    const float* Wk = (const float*)d_in[4];
    const float* bk = (const float*)d_in[5];
    const float* Wv = (const float*)d_in[6];
    const float* bv = (const float*)d_in[7];
    const float* Wo = (const float*)d_in[8];
    const float* bo = (const float*)d_in[9];
    float* outp = (float*)d_out;

    char* w = (char*)d_ws;
    ushort_t* WTall = (ushort_t*)w;               // 768*256*2      = 393216
    ushort_t* WoT   = (ushort_t*)(w + 393216);    // 256*256*2      = 131072
    float*    biasC = (float*)(w + 524288);       // 7*768*4        = 21504
    const size_t fixed = 557056;

    // choose slab count so ws fits: qkvT = 768*7*Ps*2, ctx = 7*Ps*256*2
    int s = 1;
    for (; s < 16; s *= 2) {
        size_t Ps_ = (size_t)NPOSC / s;
        size_t need = fixed + 768ull * 7 * Ps_ * 2 + 7ull * Ps_ * 256 * 2;
        if (need <= ws_size) break;
    }
    int Ps = NPOSC / s;
    ushort_t* qkvT = (ushort_t*)(w + fixed);
    ushort_t* ctxp = (ushort_t*)(w + fixed + (size_t)768 * 7 * Ps * 2);

    prep_kernel<<<85, 256, 0, stream>>>(Wq, Wk, Wv, Wo, bq, bk, bv, temb,
                                        WTall, WoT, biasC);
    for (int sl = 0; sl < s; ++sl) {
        int posBase = sl * Ps;
        qkv_kernel<<<dim3(Ps / 128, 7), 256, 0, stream>>>(frames, temb, WTall, biasC,
                                                          qkvT, posBase, Ps);
        attn_kernel<<<dim3(Ps / 256, 8), 256, 0, stream>>>(qkvT, ctxp, Ps);
        out_kernel<<<dim3(7 * Ps / 128, 2), 256, 0, stream>>>(ctxp, WoT, bo, outp,
                                                              posBase, Ps);
    }
}

// Round 3
// 858.173 us; speedup vs baseline: 1.5701x; 1.0521x over previous
//
#include <hip/hip_runtime.h>
#include <stdint.h>

#define TT 7
#define CC 256
#define NPOSC 36864   // B*H*W = 4*96*96

typedef unsigned int uint;
typedef unsigned short ushort_t;
typedef __attribute__((ext_vector_type(8))) short short8;
typedef __attribute__((ext_vector_type(4))) float f32x4;

__device__ inline float bf2f(ushort_t u) {
    union { uint i; float f; } v; v.i = ((uint)u) << 16; return v.f;
}
__device__ inline ushort_t f2bf(float f) {
    union { float f; uint i; } v; v.f = f;
    uint i = v.i;
    return (ushort_t)((i + 0x7FFFu + ((i >> 16) & 1u)) >> 16);
}
__device__ inline uint pack2(float a, float b) {
    return (uint)f2bf(a) | (((uint)f2bf(b)) << 16);
}
__device__ inline short8 as_s8(uint4 v) {
    union { uint4 u; short8 s; } x; x.u = v; return x.s;
}

// ---------------------------------------------------------------------------
// prep: blocks 0..63  -> 64x64-tile transposes (fp32 -> bf16) of Wq,Wk,Wv
//                        -> WTall[768][256] (XOR-SWIZZLED: element (R, ushort U)
//                        stored at R*256 + (U ^ ((R&7)<<3)) so a linear
//                        global_load_lds produces a bank-conflict-free LDS
//                        tile); Wo -> WoT[c][nd] (linear, unchanged)
//       blocks 64..84 -> biasC[t][768] = {bq, bk, bv - emb[t]*Wv}   (fp32)
// ---------------------------------------------------------------------------
__global__ void prep_kernel(const float* __restrict__ Wq, const float* __restrict__ Wk,
                            const float* __restrict__ Wv, const float* __restrict__ Wo,
                            const float* __restrict__ bq, const float* __restrict__ bk,
                            const float* __restrict__ bv, const float* __restrict__ temb,
                            ushort_t* __restrict__ WTall, ushort_t* __restrict__ WoT,
                            float* __restrict__ biasC)
{
    int bx = blockIdx.x, tid = threadIdx.x;
    if (bx < 64) {
        __shared__ __align__(16) ushort_t tl[64][72];   // 72*2=144B row stride (16B-mult)
        int m = bx >> 4, tile = bx & 15;
        int tr = (tile >> 2) * 64, tc = (tile & 3) * 64;
        const float* src = (m == 0) ? Wq : (m == 1) ? Wk : (m == 2) ? Wv : Wo;
        ushort_t* dst = (m < 3) ? (WTall + m * 65536) : WoT;
        int lr = tid >> 2, lc = (tid & 3) * 16;
        const float* sp = src + (size_t)(tr + lr) * 256 + tc + lc;
        #pragma unroll
        for (int q = 0; q < 4; ++q) {
            float4 x = *(const float4*)(sp + q * 4);
            tl[lr][lc + q * 4 + 0] = f2bf(x.x);
            tl[lr][lc + q * 4 + 1] = f2bf(x.y);
            tl[lr][lc + q * 4 + 2] = f2bf(x.z);
            tl[lr][lc + q * 4 + 3] = f2bf(x.w);
        }
        __syncthreads();
        uint w[8];
        #pragma unroll
        for (int j = 0; j < 8; ++j) {
            ushort_t e0 = tl[lc + 2 * j][lr];
            ushort_t e1 = tl[lc + 2 * j + 1][lr];
            w[j] = (uint)e0 | ((uint)e1 << 16);
        }
        uint4 o0, o1;
        o0.x = w[0]; o0.y = w[1]; o0.z = w[2]; o0.w = w[3];
        o1.x = w[4]; o1.y = w[5]; o1.z = w[6]; o1.w = w[7];
        int row = tc + lr;                       // output row (nd for m<3, c for m==3)
        int sw = (m < 3) ? ((row & 7) << 3) : 0; // XOR swizzle, ushort units (bits 3..5)
        int c0u = tr + lc;                       // logical ushort col (16-aligned)
        *(uint4*)(dst + (size_t)row * 256 + (c0u ^ sw)) = o0;
        *(uint4*)(dst + (size_t)row * 256 + ((c0u + 8) ^ sw)) = o1;
    } else {
        int gid = (bx - 64) * 256 + tid;   // 0..5375
        int t = gid / 768, j = gid % 768;
        float val;
        if (j < 256) {
            val = bq[j];
        } else if (j < 512) {
            val = bk[j - 256];
        } else {
            int nd = j - 512;
            float acc = bv[nd];
            for (int c = 0; c < 256; ++c)
                acc -= temb[t * 256 + c] * Wv[(size_t)c * 256 + nd];
            val = acc;   // bv - emb*Wv  => V = (X+emb)*Wv + biasC
        }
        biasC[t * 768 + j] = val;
    }
}

// ---------------------------------------------------------------------------
// K1: qkvT[nd=768][t][pos] = WTall[nd][c] x bf16(frames[t][pos][c] + emb[t][c])
//                            + biasC     (fp32 in, bf16 out)
// A staged in 64nd x 256c chunks (32KB) via global_load_lds width=16,
// double-buffered, ONE barrier per chunk (12 total, was 96). WTall is
// pre-swizzled in global so the linear DMA yields a conflict-free LDS tile;
// fragment ds_read_b128 applies the matching XOR. No pointer arrays (rule #20).
// ---------------------------------------------------------------------------
__launch_bounds__(256, 2)
__global__ void qkv_kernel(const float* __restrict__ frames, const float* __restrict__ temb,
                           const ushort_t* __restrict__ WTsw, const float* __restrict__ biasC,
                           ushort_t* __restrict__ qkvT, int posBase, int Ps)
{
    int t = blockIdx.y;
    int pos0l = blockIdx.x * 128;
    int tid = threadIdx.x;
    int wave = tid >> 6, lane = tid & 63;
    int mh = wave >> 1, nh = wave & 1;
    int l15 = lane & 15, lg = lane >> 4;

    __shared__ __align__(16) ushort_t Atile[2][64][256];   // 2 x 32KB, swizzled layout

    // --- load B fragments: KQ^T = frames + emb, 64 pos x 256 c per wave ---
    uint4 Breg[4][8];
    {
        const float* fb = frames + ((size_t)t * NPOSC + posBase + pos0l + nh * 64) * 256;
        #pragma unroll
        for (int kc = 0; kc < 8; ++kc) {
            float4 e0 = *(const float4*)(temb + t * 256 + kc * 32 + lg * 8);
            float4 e1 = *(const float4*)(temb + t * 256 + kc * 32 + lg * 8 + 4);
            #pragma unroll
            for (int nt = 0; nt < 4; ++nt) {
                const float* xp = fb + (size_t)(nt * 16 + l15) * 256 + kc * 32 + lg * 8;
                float4 x0 = *(const float4*)(xp);
                float4 x1 = *(const float4*)(xp + 4);
                uint4 r;
                r.x = pack2(x0.x + e0.x, x0.y + e0.y);
                r.y = pack2(x0.z + e0.z, x0.w + e0.w);
                r.z = pack2(x1.x + e1.x, x1.y + e1.y);
                r.w = pack2(x1.z + e1.z, x1.w + e1.w);
                Breg[nt][kc] = r;
            }
        }
    }

    f32x4 acc[2][4];
    const f32x4 z4 = {0.f, 0.f, 0.f, 0.f};
    #pragma unroll
    for (int mt = 0; mt < 2; ++mt)
        #pragma unroll
        for (int nt = 0; nt < 4; ++nt) acc[mt][nt] = z4;

    // per-wave DMA cursor: wave w covers bytes [w*8K, (w+1)*8K) of each 32KB chunk
    const char* wsrc = (const char*)WTsw + (size_t)(wave * 8) * 1024 + (size_t)lane * 16;
    char* lbase = (char*)&Atile[0][0][0] + (size_t)(wave * 8) * 1024;

    // prologue: stage chunk 0 into buffer 0
    #pragma unroll
    for (int i = 0; i < 8; ++i)
        __builtin_amdgcn_global_load_lds(
            (const __attribute__((address_space(1))) void*)(wsrc + i * 1024),
            (__attribute__((address_space(3))) void*)(lbase + i * 1024), 16, 0, 0);
    __syncthreads();

    for (int ndc = 0; ndc < 12; ++ndc) {
        int buf = ndc & 1;
        // issue next chunk's DMA first: latency hides under 64 MFMAs + epilogue
        if (ndc < 11) {
            const char* src = wsrc + (size_t)(ndc + 1) * 32768;
            char* nb = lbase + (size_t)(buf ^ 1) * 32768;
            #pragma unroll
            for (int i = 0; i < 8; ++i)
                __builtin_amdgcn_global_load_lds(
                    (const __attribute__((address_space(1))) void*)(src + i * 1024),
                    (__attribute__((address_space(3))) void*)(nb + i * 1024), 16, 0, 0);
        }
        #pragma unroll
        for (int kc = 0; kc < 8; ++kc) {
            uint4 af[2];
            #pragma unroll
            for (int mt = 0; mt < 2; ++mt) {
                int r = mh * 32 + mt * 16 + l15;
                int colb = (kc * 64 + lg * 16) ^ ((r & 7) << 4);   // matching XOR
                af[mt] = *(const uint4*)((const char*)&Atile[buf][r][0] + colb);
            }
            #pragma unroll
            for (int mt = 0; mt < 2; ++mt)
                #pragma unroll
                for (int nt = 0; nt < 4; ++nt)
                    acc[mt][nt] = __builtin_amdgcn_mfma_f32_16x16x32_bf16(
                        as_s8(af[mt]), as_s8(Breg[nt][kc]), acc[mt][nt], 0, 0, 0);
        }
        // epilogue for this nd-chunk (64 rows)
        #pragma unroll
        for (int mt = 0; mt < 2; ++mt) {
            int ndbase = ndc * 64 + mh * 32 + mt * 16 + lg * 4;
            float bi[4];
            #pragma unroll
            for (int i = 0; i < 4; ++i) bi[i] = biasC[t * 768 + ndbase + i];
            #pragma unroll
            for (int nt = 0; nt < 4; ++nt) {
                int posl = pos0l + nh * 64 + nt * 16 + l15;
                #pragma unroll
                for (int i = 0; i < 4; ++i) {
                    float v = acc[mt][nt][i] + bi[i];
                    qkvT[((size_t)(ndbase + i) * 7 + t) * Ps + posl] = f2bf(v);
                }
                acc[mt][nt] = z4;
            }
        }
        __syncthreads();   // drains next-chunk DMA (vmcnt) + all reads of buf
    }
}

// ---------------------------------------------------------------------------
// K2: attention per (pos, head). lane = position -> fully coalesced loads.
// qkvT rows: q = nd, k = 256+nd, v = 512+nd
// ctx written TRANSPOSED as ctxT[c][a*Ps+pos]  (pos-contiguous scalar stores)
// ---------------------------------------------------------------------------
__global__ void attn_kernel(const ushort_t* __restrict__ qkvT, ushort_t* __restrict__ ctxT, int Ps)
{
    int n = blockIdx.y;
    int pos = blockIdx.x * 256 + threadIdx.x;
    const float scale = 0.17677669529663687f;      // 1/sqrt(32)
    float s[7][7];
    #pragma unroll
    for (int a = 0; a < 7; ++a)
        #pragma unroll
        for (int b = 0; b < 7; ++b) s[a][b] = 0.f;

    const ushort_t* qp = qkvT + ((size_t)(n * 32) * 7) * Ps + pos;
    const ushort_t* kp = qkvT + ((size_t)(256 + n * 32) * 7) * Ps + pos;

    for (int d = 0; d < 32; ++d) {
        float qv[7], kv[7];
        #pragma unroll
        for (int i = 0; i < 7; ++i) qv[i] = bf2f(qp[(size_t)(d * 7 + i) * Ps]);
        #pragma unroll
        for (int i = 0; i < 7; ++i) kv[i] = bf2f(kp[(size_t)(d * 7 + i) * Ps]);
        #pragma unroll
        for (int a = 0; a < 7; ++a)
            #pragma unroll
            for (int b = 0; b < 7; ++b) s[a][b] += qv[a] * kv[b];
    }

    #pragma unroll
    for (int a = 0; a < 7; ++a) {
        float mx = -1e30f;
        #pragma unroll
        for (int b = 0; b < 7; ++b) { s[a][b] *= scale; mx = fmaxf(mx, s[a][b]); }
        float sum = 0.f;
        #pragma unroll
        for (int b = 0; b < 7; ++b) {
            float e = exp2f((s[a][b] - mx) * 1.4426950408889634f);
            s[a][b] = e; sum += e;
        }
        float r = 1.0f / sum;
        #pragma unroll
        for (int b = 0; b < 7; ++b) s[a][b] *= r;
    }

    const ushort_t* vp = qkvT + ((size_t)(512 + n * 32) * 7) * Ps + pos;
    const size_t K7P = (size_t)7 * Ps;
    ushort_t* cb = ctxT + (size_t)(n * 32) * K7P + pos;

    #pragma unroll
    for (int dc = 0; dc < 4; ++dc) {
        float o[7][8];
        #pragma unroll
        for (int a = 0; a < 7; ++a)
            #pragma unroll
            for (int j = 0; j < 8; ++j) o[a][j] = 0.f;
        #pragma unroll
        for (int kt = 0; kt < 7; ++kt) {
            float vv[8];
            #pragma unroll
            for (int j = 0; j < 8; ++j)
                vv[j] = bf2f(vp[(size_t)((dc * 8 + j) * 7 + kt) * Ps]);
            #pragma unroll
            for (int a = 0; a < 7; ++a)
                #pragma unroll
                for (int j = 0; j < 8; ++j) o[a][j] += s[a][kt] * vv[j];
        }
        // transposed store: channel-major, pos contiguous -> coalesced
        #pragma unroll
        for (int j = 0; j < 8; ++j) {
            ushort_t* cj = cb + (size_t)(dc * 8 + j) * K7P;
            #pragma unroll
            for (int a = 0; a < 7; ++a)
                cj[(size_t)a * Ps] = f2bf(o[a][j]);
        }
    }
}

// ---------------------------------------------------------------------------
// K3: out[t*NPOS+pos][c] = ctxT[nd][tp] x Wo[nd][c] + bo[c]   (fp32 output)
// A = ctxT (pos-contig global reads, transposed into LDS with XOR col-group
// swizzle: stored group = logical group ^ ((row>>3)&3)), B = WoT (k-contig).
// ---------------------------------------------------------------------------
__launch_bounds__(256, 2)
__global__ void out_kernel(const ushort_t* __restrict__ ctxT, const ushort_t* __restrict__ WoT,
                           const float* __restrict__ bo, float* __restrict__ outp,
                           int posBase, int Ps)
{
    int rows0 = blockIdx.x * 128;
    int c0 = blockIdx.y * 128;
    int tid = threadIdx.x, wave = tid >> 6, lane = tid & 63;
    int mh = wave >> 1, nh = wave & 1;
    int l15 = lane & 15, lg = lane >> 4;
    const size_t K7P = (size_t)7 * Ps;

    __shared__ __align__(16) ushort_t At[2][128][40];
    __shared__ __align__(16) ushort_t Bt[2][128][40];

    // A staging mapping: each thread owns one nd column, 2x8 consecutive rows
    int ndl = tid >> 3;          // 0..31  (k within chunk)
    int rg  = tid & 7;           // 0..7   (row octet)
    int csw = ((((ndl >> 3) ^ (rg & 3)) << 3) | (ndl & 7));

    f32x4 acc[4][4];
    const f32x4 z4 = {0.f, 0.f, 0.f, 0.f};
    #pragma unroll
    for (int mt = 0; mt < 4; ++mt)
        #pragma unroll
        for (int nt = 0; nt < 4; ++nt) acc[mt][nt] = z4;

    // stage kc=0
    {
        const ushort_t* ap = ctxT + (size_t)ndl * K7P + rows0 + rg * 8;
        union { uint4 u; ushort_t s[8]; } ua, ub;
        ua.u = *(const uint4*)ap;
        ub.u = *(const uint4*)(ap + 64);
        #pragma unroll
        for (int i = 0; i < 8; ++i) {
            At[0][rg * 8 + i][csw] = ua.s[i];
            At[0][64 + rg * 8 + i][csw] = ub.s[i];
        }
        #pragma unroll
        for (int p = 0; p < 2; ++p) {
            int ch = p * 256 + tid, row = ch >> 2, q4 = ch & 3;
            uint4 bv_ = *(const uint4*)(WoT + (size_t)(c0 + row) * 256 + q4 * 8);
            *(uint4*)&Bt[0][row][q4 * 8] = bv_;
        }
    }

    #pragma unroll
    for (int kc = 0; kc < 8; ++kc) {
        int buf = kc & 1;
        uint4 na0, na1, nb[2];
        if (kc < 7) {
            const ushort_t* ap = ctxT + (size_t)((kc + 1) * 32 + ndl) * K7P + rows0 + rg * 8;
            na0 = *(const uint4*)ap;
            na1 = *(const uint4*)(ap + 64);
            #pragma unroll
            for (int p = 0; p < 2; ++p) {
                int ch = p * 256 + tid, row = ch >> 2, q4 = ch & 3;
                nb[p] = *(const uint4*)(WoT + (size_t)(c0 + row) * 256 + (kc + 1) * 32 + q4 * 8);
            }
        }
        __syncthreads();
        if (kc < 7) {
            union { uint4 u; ushort_t s[8]; } ua, ub;
            ua.u = na0; ub.u = na1;
            #pragma unroll
            for (int i = 0; i < 8; ++i) {
                At[buf ^ 1][rg * 8 + i][csw] = ua.s[i];
                At[buf ^ 1][64 + rg * 8 + i][csw] = ub.s[i];
            }
            #pragma unroll
            for (int p = 0; p < 2; ++p) {
                int ch = p * 256 + tid, row = ch >> 2, q4 = ch & 3;
                *(uint4*)&Bt[buf ^ 1][row][q4 * 8] = nb[p];
            }
        }
        uint4 af[4], bfr[4];
        #pragma unroll
        for (int mt = 0; mt < 4; ++mt) {
            int r = mh * 64 + mt * 16 + l15;
            af[mt] = *(const uint4*)&At[buf][r][(lg ^ ((r >> 3) & 3)) << 3];
        }
        #pragma unroll
        for (int nt = 0; nt < 4; ++nt)
            bfr[nt] = *(const uint4*)&Bt[buf][nh * 64 + nt * 16 + l15][lg * 8];
        #pragma unroll
        for (int mt = 0; mt < 4; ++mt)
            #pragma unroll
            for (int nt = 0; nt < 4; ++nt)
                acc[mt][nt] = __builtin_amdgcn_mfma_f32_16x16x32_bf16(
                    as_s8(af[mt]), as_s8(bfr[nt]), acc[mt][nt], 0, 0, 0);
    }

    int t = rows0 / Ps;            // block entirely inside one t (Ps % 128 == 0)
    int prow = rows0 - t * Ps;
    size_t obase = (size_t)t * NPOSC + posBase + prow;
    #pragma unroll
    for (int nt = 0; nt < 4; ++nt) {
        int col = c0 + nh * 64 + nt * 16 + l15;
        float bov = bo[col];
        #pragma unroll
        for (int mt = 0; mt < 4; ++mt) {
            #pragma unroll
            for (int i = 0; i < 4; ++i) {
                int r = mh * 64 + mt * 16 + lg * 4 + i;
                outp[(obase + r) * 256 + col] = acc[mt][nt][i] + bov;
            }
        }
    }
}

// ---------------------------------------------------------------------------
extern "C" void kernel_launch(void* const* d_in, const int* in_sizes, int n_in,
                              void* d_out, int out_size, void* d_ws, size_t ws_size,
                              hipStream_t stream)
{
    const float* frames = (const float*)d_in[0];
    const float* temb   = (const float*)d_in[1];
    const float* Wq = (const float*)d_in[2];
    const float* bq = (const float*)d_in[3];
    const float* Wk = (const float*)d_in[4];
    const float* bk = (const float*)d_in[5];
    const float* Wv = (const float*)d_in[6];
    const float* bv = (const float*)d_in[7];
    const float* Wo = (const float*)d_in[8];
    const float* bo = (const float*)d_in[9];
    float* outp = (float*)d_out;

    char* w = (char*)d_ws;
    ushort_t* WTall = (ushort_t*)w;               // 768*256*2      = 393216
    ushort_t* WoT   = (ushort_t*)(w + 393216);    // 256*256*2      = 131072
    float*    biasC = (float*)(w + 524288);       // 7*768*4        = 21504
    const size_t fixed = 557056;

    // choose slab count so ws fits: qkvT = 768*7*Ps*2, ctx = 7*Ps*256*2
    int s = 1;
    for (; s < 16; s *= 2) {
        size_t Ps_ = (size_t)NPOSC / s;
        size_t need = fixed + 768ull * 7 * Ps_ * 2 + 7ull * Ps_ * 256 * 2;
        if (need <= ws_size) break;
    }
    int Ps = NPOSC / s;
    ushort_t* qkvT = (ushort_t*)(w + fixed);
    ushort_t* ctxp = (ushort_t*)(w + fixed + (size_t)768 * 7 * Ps * 2);

    prep_kernel<<<85, 256, 0, stream>>>(Wq, Wk, Wv, Wo, bq, bk, bv, temb,
                                        WTall, WoT, biasC);
    for (int sl = 0; sl < s; ++sl) {
        int posBase = sl * Ps;
        qkv_kernel<<<dim3(Ps / 128, 7), 256, 0, stream>>>(frames, temb, WTall, biasC,
                                                          qkvT, posBase, Ps);
        attn_kernel<<<dim3(Ps / 256, 8), 256, 0, stream>>>(qkvT, ctxp, Ps);
        out_kernel<<<dim3(7 * Ps / 128, 2), 256, 0, stream>>>(ctxp, WoT, bo, outp,
                                                              posBase, Ps);
    }
}

// Round 4
// 786.707 us; speedup vs baseline: 1.7128x; 1.0908x over previous
//
#include <hip/hip_runtime.h>
#include <stdint.h>

#define TT 7
#define CC 256
#define NPOSC 36864   // B*H*W = 4*96*96

typedef unsigned int uint;
typedef unsigned short ushort_t;
typedef __attribute__((ext_vector_type(8))) short short8;
typedef __attribute__((ext_vector_type(4))) float f32x4;

__device__ inline float bf2f(ushort_t u) {
    union { uint i; float f; } v; v.i = ((uint)u) << 16; return v.f;
}
__device__ inline ushort_t f2bf(float f) {
    union { float f; uint i; } v; v.f = f;
    uint i = v.i;
    return (ushort_t)((i + 0x7FFFu + ((i >> 16) & 1u)) >> 16);
}
__device__ inline uint pack2(float a, float b) {
    return (uint)f2bf(a) | (((uint)f2bf(b)) << 16);
}
// packed f32->bf16 (RNE, identical rounding to f2bf for finite inputs)
__device__ inline uint cvtpk(float lo, float hi) {
    uint r;
    asm("v_cvt_pk_bf16_f32 %0, %1, %2" : "=v"(r) : "v"(lo), "v"(hi));
    return r;
}
__device__ inline short8 as_s8(uint4 v) {
    union { uint4 u; short8 s; } x; x.u = v; return x.s;
}

// ---------------------------------------------------------------------------
// prep: blocks 0..63  -> 64x64-tile transposes (fp32 -> bf16) of Wq,Wk,Wv
//                        -> WTall[768][256] (XOR-SWIZZLED: element (R, ushort U)
//                        stored at R*256 + (U ^ ((R&7)<<3)) so a linear
//                        global_load_lds produces a bank-conflict-free LDS
//                        tile); Wo -> WoT[c][nd] (linear, unchanged)
//       blocks 64..84 -> biasC[t][768] = {bq, bk, bv - emb[t]*Wv}   (fp32)
// ---------------------------------------------------------------------------
__global__ void prep_kernel(const float* __restrict__ Wq, const float* __restrict__ Wk,
                            const float* __restrict__ Wv, const float* __restrict__ Wo,
                            const float* __restrict__ bq, const float* __restrict__ bk,
                            const float* __restrict__ bv, const float* __restrict__ temb,
                            ushort_t* __restrict__ WTall, ushort_t* __restrict__ WoT,
                            float* __restrict__ biasC)
{
    int bx = blockIdx.x, tid = threadIdx.x;
    if (bx < 64) {
        __shared__ __align__(16) ushort_t tl[64][72];   // 72*2=144B row stride (16B-mult)
        int m = bx >> 4, tile = bx & 15;
        int tr = (tile >> 2) * 64, tc = (tile & 3) * 64;
        const float* src = (m == 0) ? Wq : (m == 1) ? Wk : (m == 2) ? Wv : Wo;
        ushort_t* dst = (m < 3) ? (WTall + m * 65536) : WoT;
        int lr = tid >> 2, lc = (tid & 3) * 16;
        const float* sp = src + (size_t)(tr + lr) * 256 + tc + lc;
        #pragma unroll
        for (int q = 0; q < 4; ++q) {
            float4 x = *(const float4*)(sp + q * 4);
            tl[lr][lc + q * 4 + 0] = f2bf(x.x);
            tl[lr][lc + q * 4 + 1] = f2bf(x.y);
            tl[lr][lc + q * 4 + 2] = f2bf(x.z);
            tl[lr][lc + q * 4 + 3] = f2bf(x.w);
        }
        __syncthreads();
        uint w[8];
        #pragma unroll
        for (int j = 0; j < 8; ++j) {
            ushort_t e0 = tl[lc + 2 * j][lr];
            ushort_t e1 = tl[lc + 2 * j + 1][lr];
            w[j] = (uint)e0 | ((uint)e1 << 16);
        }
        uint4 o0, o1;
        o0.x = w[0]; o0.y = w[1]; o0.z = w[2]; o0.w = w[3];
        o1.x = w[4]; o1.y = w[5]; o1.z = w[6]; o1.w = w[7];
        int row = tc + lr;                       // output row (nd for m<3, c for m==3)
        int sw = (m < 3) ? ((row & 7) << 3) : 0; // XOR swizzle, ushort units (bits 3..5)
        int c0u = tr + lc;                       // logical ushort col (16-aligned)
        *(uint4*)(dst + (size_t)row * 256 + (c0u ^ sw)) = o0;
        *(uint4*)(dst + (size_t)row * 256 + ((c0u + 8) ^ sw)) = o1;
    } else {
        int gid = (bx - 64) * 256 + tid;   // 0..5375
        int t = gid / 768, j = gid % 768;
        float val;
        if (j < 256) {
            val = bq[j];
        } else if (j < 512) {
            val = bk[j - 256];
        } else {
            int nd = j - 512;
            float acc = bv[nd];
            for (int c = 0; c < 256; ++c)
                acc -= temb[t * 256 + c] * Wv[(size_t)c * 256 + nd];
            val = acc;   // bv - emb*Wv  => V = (X+emb)*Wv + biasC
        }
        biasC[t * 768 + j] = val;
    }
}

// ---------------------------------------------------------------------------
// K1: qkvT[nd=768][t][pos] = WTall[nd][c] x bf16(frames[t][pos][c] + emb[t][c])
//                            + biasC     (fp32 in, bf16 out)
// Chunks of 32 nd x 256 c (16KB) via global_load_lds width=16, double-buffered
// (32KB). Waves split by POS QUARTER (Breg = 64 VGPR). Per-wave LDS transpose
// tile for the epilogue -> uint4 stores (64B row segments). cvt_pk for all
// f32->bf16 pair conversions. 43KB LDS total -> 3 blocks/CU.
// ---------------------------------------------------------------------------
__launch_bounds__(256, 3)
__global__ void qkv_kernel(const float* __restrict__ frames, const float* __restrict__ temb,
                           const ushort_t* __restrict__ WTsw, const float* __restrict__ biasC,
                           ushort_t* __restrict__ qkvT, int posBase, int Ps)
{
    int t = blockIdx.y;
    int pos0l = blockIdx.x * 128;
    int tid = threadIdx.x;
    int wave = tid >> 6, lane = tid & 63;
    int l15 = lane & 15, lg = lane >> 4;

    __shared__ __align__(16) ushort_t Atile[2][32][256];   // 2 x 16KB, swizzled layout
    __shared__ __align__(16) ushort_t Ttile[4][32][40];    // per-wave transpose tile

    // --- load B fragments: X = frames + emb, 32 pos x 256 c per wave ---
    uint4 Breg[2][8];
    {
        const float* fb = frames + ((size_t)t * NPOSC + posBase + pos0l + wave * 32) * 256;
        #pragma unroll
        for (int kc = 0; kc < 8; ++kc) {
            float4 e0 = *(const float4*)(temb + t * 256 + kc * 32 + lg * 8);
            float4 e1 = *(const float4*)(temb + t * 256 + kc * 32 + lg * 8 + 4);
            #pragma unroll
            for (int nt = 0; nt < 2; ++nt) {
                const float* xp = fb + (size_t)(nt * 16 + l15) * 256 + kc * 32 + lg * 8;
                float4 x0 = *(const float4*)(xp);
                float4 x1 = *(const float4*)(xp + 4);
                uint4 r;
                r.x = cvtpk(x0.x + e0.x, x0.y + e0.y);
                r.y = cvtpk(x0.z + e0.z, x0.w + e0.w);
                r.z = cvtpk(x1.x + e1.x, x1.y + e1.y);
                r.w = cvtpk(x1.z + e1.z, x1.w + e1.w);
                Breg[nt][kc] = r;
            }
        }
    }

    f32x4 acc[2][2];
    const f32x4 z4 = {0.f, 0.f, 0.f, 0.f};
    #pragma unroll
    for (int mt = 0; mt < 2; ++mt)
        #pragma unroll
        for (int nt = 0; nt < 2; ++nt) acc[mt][nt] = z4;

    // per-wave DMA cursor: wave w covers bytes [w*4K, (w+1)*4K) of each 16KB chunk
    const char* wsrc = (const char*)WTsw + (size_t)(wave * 4) * 1024 + (size_t)lane * 16;
    char* lbase = (char*)&Atile[0][0][0] + (size_t)(wave * 4) * 1024;

    // prologue: stage chunk 0 into buffer 0
    #pragma unroll
    for (int i = 0; i < 4; ++i)
        __builtin_amdgcn_global_load_lds(
            (const __attribute__((address_space(1))) void*)(wsrc + i * 1024),
            (__attribute__((address_space(3))) void*)(lbase + i * 1024), 16, 0, 0);
    __syncthreads();

    for (int ndc = 0; ndc < 24; ++ndc) {
        int buf = ndc & 1;
        // issue next chunk's DMA first: latency hides under MFMAs + epilogue
        if (ndc < 23) {
            const char* src = wsrc + (size_t)(ndc + 1) * 16384;
            char* nb = lbase + (size_t)(buf ^ 1) * 16384;
            #pragma unroll
            for (int i = 0; i < 4; ++i)
                __builtin_amdgcn_global_load_lds(
                    (const __attribute__((address_space(1))) void*)(src + i * 1024),
                    (__attribute__((address_space(3))) void*)(nb + i * 1024), 16, 0, 0);
        }
        #pragma unroll
        for (int kc = 0; kc < 8; ++kc) {
            uint4 af[2];
            #pragma unroll
            for (int mt = 0; mt < 2; ++mt) {
                int r = mt * 16 + l15;
                int colb = (kc * 64 + lg * 16) ^ ((r & 7) << 4);   // matching XOR
                af[mt] = *(const uint4*)((const char*)&Atile[buf][r][0] + colb);
            }
            #pragma unroll
            for (int mt = 0; mt < 2; ++mt)
                #pragma unroll
                for (int nt = 0; nt < 2; ++nt)
                    acc[mt][nt] = __builtin_amdgcn_mfma_f32_16x16x32_bf16(
                        as_s8(af[mt]), as_s8(Breg[nt][kc]), acc[mt][nt], 0, 0, 0);
        }
        // epilogue: bias + bf16 -> per-wave LDS transpose tile -> wide stores
        #pragma unroll
        for (int mt = 0; mt < 2; ++mt) {
            int ndbase = ndc * 32 + mt * 16 + lg * 4;
            float b0 = biasC[t * 768 + ndbase + 0];
            float b1 = biasC[t * 768 + ndbase + 1];
            float b2 = biasC[t * 768 + ndbase + 2];
            float b3 = biasC[t * 768 + ndbase + 3];
            #pragma unroll
            for (int nt = 0; nt < 2; ++nt) {
                int pl = nt * 16 + l15;
                uint p0 = cvtpk(acc[mt][nt][0] + b0, acc[mt][nt][1] + b1);
                uint p1 = cvtpk(acc[mt][nt][2] + b2, acc[mt][nt][3] + b3);
                int nl = mt * 16 + lg * 4;
                Ttile[wave][nl + 0][pl] = (ushort_t)p0;
                Ttile[wave][nl + 1][pl] = (ushort_t)(p0 >> 16);
                Ttile[wave][nl + 2][pl] = (ushort_t)p1;
                Ttile[wave][nl + 3][pl] = (ushort_t)(p1 >> 16);
                acc[mt][nt] = z4;
            }
        }
        // per-wave tile: no barrier needed (same-wave LDS ops are ordered)
        #pragma unroll
        for (int r = 0; r < 2; ++r) {
            int ndr = r * 16 + (lane >> 2);
            int seg = lane & 3;
            uint4 v = *(const uint4*)&Ttile[wave][ndr][seg * 8];
            int nd = ndc * 32 + ndr;
            *(uint4*)(qkvT + ((size_t)nd * 7 + t) * Ps + pos0l + wave * 32 + seg * 8) = v;
        }
        __syncthreads();   // drains next-chunk DMA (vmcnt) + all reads of buf
    }
}

// ---------------------------------------------------------------------------
// K2: attention per (pos, head). lane = position -> fully coalesced loads.
// qkvT rows: q = nd, k = 256+nd, v = 512+nd
// ctx written TRANSPOSED as ctxT[c][a*Ps+pos]  (pos-contiguous scalar stores)
// launch_bounds(256,4) = 128 VGPR budget; PV chunked at 4 channels so peak
// live set (~95) fits -> no scratch spills.
// ---------------------------------------------------------------------------
__launch_bounds__(256, 4)
__global__ void attn_kernel(const ushort_t* __restrict__ qkvT, ushort_t* __restrict__ ctxT, int Ps)
{
    int n = blockIdx.y;
    int pos = blockIdx.x * 256 + threadIdx.x;
    const float scale = 0.17677669529663687f;      // 1/sqrt(32)
    float s[7][7];
    #pragma unroll
    for (int a = 0; a < 7; ++a)
        #pragma unroll
        for (int b = 0; b < 7; ++b) s[a][b] = 0.f;

    const ushort_t* qp = qkvT + ((size_t)(n * 32) * 7) * Ps + pos;
    const ushort_t* kp = qkvT + ((size_t)(256 + n * 32) * 7) * Ps + pos;

    for (int d = 0; d < 32; ++d) {
        float qv[7], kv[7];
        #pragma unroll
        for (int i = 0; i < 7; ++i) qv[i] = bf2f(qp[(size_t)(d * 7 + i) * Ps]);
        #pragma unroll
        for (int i = 0; i < 7; ++i) kv[i] = bf2f(kp[(size_t)(d * 7 + i) * Ps]);
        #pragma unroll
        for (int a = 0; a < 7; ++a)
            #pragma unroll
            for (int b = 0; b < 7; ++b) s[a][b] += qv[a] * kv[b];
    }

    #pragma unroll
    for (int a = 0; a < 7; ++a) {
        float mx = -1e30f;
        #pragma unroll
        for (int b = 0; b < 7; ++b) { s[a][b] *= scale; mx = fmaxf(mx, s[a][b]); }
        float sum = 0.f;
        #pragma unroll
        for (int b = 0; b < 7; ++b) {
            float e = exp2f((s[a][b] - mx) * 1.4426950408889634f);
            s[a][b] = e; sum += e;
        }
        float r = 1.0f / sum;
        #pragma unroll
        for (int b = 0; b < 7; ++b) s[a][b] *= r;
    }

    const ushort_t* vp = qkvT + ((size_t)(512 + n * 32) * 7) * Ps + pos;
    const size_t K7P = (size_t)7 * Ps;
    ushort_t* cb = ctxT + (size_t)(n * 32) * K7P + pos;

    #pragma unroll 1
    for (int dc = 0; dc < 8; ++dc) {      // 4 channels per iteration
        float o[7][4];
        #pragma unroll
        for (int a = 0; a < 7; ++a)
            #pragma unroll
            for (int j = 0; j < 4; ++j) o[a][j] = 0.f;
        #pragma unroll
        for (int kt = 0; kt < 7; ++kt) {
            float vv[4];
            #pragma unroll
            for (int j = 0; j < 4; ++j)
                vv[j] = bf2f(vp[(size_t)((dc * 4 + j) * 7 + kt) * Ps]);
            #pragma unroll
            for (int a = 0; a < 7; ++a)
                #pragma unroll
                for (int j = 0; j < 4; ++j) o[a][j] += s[a][kt] * vv[j];
        }
        // transposed store: channel-major, pos contiguous -> coalesced
        #pragma unroll
        for (int j = 0; j < 4; ++j) {
            ushort_t* cj = cb + (size_t)(dc * 4 + j) * K7P;
            #pragma unroll
            for (int a = 0; a < 7; ++a)
                cj[(size_t)a * Ps] = f2bf(o[a][j]);
        }
    }
}

// ---------------------------------------------------------------------------
// K3: out[t*NPOS+pos][c] = ctxT[nd][tp] x Wo[nd][c] + bo[c]   (fp32 output)
// A = ctxT (pos-contig global reads, transposed into LDS with XOR col-group
// swizzle: stored group = logical group ^ ((row>>3)&3)), B = WoT (k-contig).
// ---------------------------------------------------------------------------
__launch_bounds__(256, 2)
__global__ void out_kernel(const ushort_t* __restrict__ ctxT, const ushort_t* __restrict__ WoT,
                           const float* __restrict__ bo, float* __restrict__ outp,
                           int posBase, int Ps)
{
    int rows0 = blockIdx.x * 128;
    int c0 = blockIdx.y * 128;
    int tid = threadIdx.x, wave = tid >> 6, lane = tid & 63;
    int mh = wave >> 1, nh = wave & 1;
    int l15 = lane & 15, lg = lane >> 4;
    const size_t K7P = (size_t)7 * Ps;

    __shared__ __align__(16) ushort_t At[2][128][40];
    __shared__ __align__(16) ushort_t Bt[2][128][40];

    // A staging mapping: each thread owns one nd column, 2x8 consecutive rows
    int ndl = tid >> 3;          // 0..31  (k within chunk)
    int rg  = tid & 7;           // 0..7   (row octet)
    int csw = ((((ndl >> 3) ^ (rg & 3)) << 3) | (ndl & 7));

    f32x4 acc[4][4];
    const f32x4 z4 = {0.f, 0.f, 0.f, 0.f};
    #pragma unroll
    for (int mt = 0; mt < 4; ++mt)
        #pragma unroll
        for (int nt = 0; nt < 4; ++nt) acc[mt][nt] = z4;

    // stage kc=0
    {
        const ushort_t* ap = ctxT + (size_t)ndl * K7P + rows0 + rg * 8;
        union { uint4 u; ushort_t s[8]; } ua, ub;
        ua.u = *(const uint4*)ap;
        ub.u = *(const uint4*)(ap + 64);
        #pragma unroll
        for (int i = 0; i < 8; ++i) {
            At[0][rg * 8 + i][csw] = ua.s[i];
            At[0][64 + rg * 8 + i][csw] = ub.s[i];
        }
        #pragma unroll
        for (int p = 0; p < 2; ++p) {
            int ch = p * 256 + tid, row = ch >> 2, q4 = ch & 3;
            uint4 bv_ = *(const uint4*)(WoT + (size_t)(c0 + row) * 256 + q4 * 8);
            *(uint4*)&Bt[0][row][q4 * 8] = bv_;
        }
    }

    #pragma unroll
    for (int kc = 0; kc < 8; ++kc) {
        int buf = kc & 1;
        uint4 na0, na1, nb[2];
        if (kc < 7) {
            const ushort_t* ap = ctxT + (size_t)((kc + 1) * 32 + ndl) * K7P + rows0 + rg * 8;
            na0 = *(const uint4*)ap;
            na1 = *(const uint4*)(ap + 64);
            #pragma unroll
            for (int p = 0; p < 2; ++p) {
                int ch = p * 256 + tid, row = ch >> 2, q4 = ch & 3;
                nb[p] = *(const uint4*)(WoT + (size_t)(c0 + row) * 256 + (kc + 1) * 32 + q4 * 8);
            }
        }
        __syncthreads();
        if (kc < 7) {
            union { uint4 u; ushort_t s[8]; } ua, ub;
            ua.u = na0; ub.u = na1;
            #pragma unroll
            for (int i = 0; i < 8; ++i) {
                At[buf ^ 1][rg * 8 + i][csw] = ua.s[i];
                At[buf ^ 1][64 + rg * 8 + i][csw] = ub.s[i];
            }
            #pragma unroll
            for (int p = 0; p < 2; ++p) {
                int ch = p * 256 + tid, row = ch >> 2, q4 = ch & 3;
                *(uint4*)&Bt[buf ^ 1][row][q4 * 8] = nb[p];
            }
        }
        uint4 af[4], bfr[4];
        #pragma unroll
        for (int mt = 0; mt < 4; ++mt) {
            int r = mh * 64 + mt * 16 + l15;
            af[mt] = *(const uint4*)&At[buf][r][(lg ^ ((r >> 3) & 3)) << 3];
        }
        #pragma unroll
        for (int nt = 0; nt < 4; ++nt)
            bfr[nt] = *(const uint4*)&Bt[buf][nh * 64 + nt * 16 + l15][lg * 8];
        #pragma unroll
        for (int mt = 0; mt < 4; ++mt)
            #pragma unroll
            for (int nt = 0; nt < 4; ++nt)
                acc[mt][nt] = __builtin_amdgcn_mfma_f32_16x16x32_bf16(
                    as_s8(af[mt]), as_s8(bfr[nt]), acc[mt][nt], 0, 0, 0);
    }

    int t = rows0 / Ps;            // block entirely inside one t (Ps % 128 == 0)
    int prow = rows0 - t * Ps;
    size_t obase = (size_t)t * NPOSC + posBase + prow;
    #pragma unroll
    for (int nt = 0; nt < 4; ++nt) {
        int col = c0 + nh * 64 + nt * 16 + l15;
        float bov = bo[col];
        #pragma unroll
        for (int mt = 0; mt < 4; ++mt) {
            #pragma unroll
            for (int i = 0; i < 4; ++i) {
                int r = mh * 64 + mt * 16 + lg * 4 + i;
                outp[(obase + r) * 256 + col] = acc[mt][nt][i] + bov;
            }
        }
    }
}

// ---------------------------------------------------------------------------
extern "C" void kernel_launch(void* const* d_in, const int* in_sizes, int n_in,
                              void* d_out, int out_size, void* d_ws, size_t ws_size,
                              hipStream_t stream)
{
    const float* frames = (const float*)d_in[0];
    const float* temb   = (const float*)d_in[1];
    const float* Wq = (const float*)d_in[2];
    const float* bq = (const float*)d_in[3];
    const float* Wk = (const float*)d_in[4];
    const float* bk = (const float*)d_in[5];
    const float* Wv = (const float*)d_in[6];
    const float* bv = (const float*)d_in[7];
    const float* Wo = (const float*)d_in[8];
    const float* bo = (const float*)d_in[9];
    float* outp = (float*)d_out;

    char* w = (char*)d_ws;
    ushort_t* WTall = (ushort_t*)w;               // 768*256*2      = 393216
    ushort_t* WoT   = (ushort_t*)(w + 393216);    // 256*256*2      = 131072
    float*    biasC = (float*)(w + 524288);       // 7*768*4        = 21504
    const size_t fixed = 557056;

    // choose slab count so ws fits: qkvT = 768*7*Ps*2, ctx = 7*Ps*256*2
    int s = 1;
    for (; s < 16; s *= 2) {
        size_t Ps_ = (size_t)NPOSC / s;
        size_t need = fixed + 768ull * 7 * Ps_ * 2 + 7ull * Ps_ * 256 * 2;
        if (need <= ws_size) break;
    }
    int Ps = NPOSC / s;
    ushort_t* qkvT = (ushort_t*)(w + fixed);
    ushort_t* ctxp = (ushort_t*)(w + fixed + (size_t)768 * 7 * Ps * 2);

    prep_kernel<<<85, 256, 0, stream>>>(Wq, Wk, Wv, Wo, bq, bk, bv, temb,
                                        WTall, WoT, biasC);
    for (int sl = 0; sl < s; ++sl) {
        int posBase = sl * Ps;
        qkv_kernel<<<dim3(Ps / 128, 7), 256, 0, stream>>>(frames, temb, WTall, biasC,
                                                          qkvT, posBase, Ps);
        attn_kernel<<<dim3(Ps / 256, 8), 256, 0, stream>>>(qkvT, ctxp, Ps);
        out_kernel<<<dim3(7 * Ps / 128, 2), 256, 0, stream>>>(ctxp, WoT, bo, outp,
                                                              posBase, Ps);
    }
}